// Round 9
// baseline (509.343 us; speedup 1.0000x reference)
//
#include <hip/hip_runtime.h>
#include <math.h>

#define BB 8
#define LAT 128
#define HH 1024
#define KK 294
#define NN 100000
#define EE 1600000
#define NSTEPS 3
#define XS_HALF 64.0f

#define NB 391      // ceil(NN/256)
#define CS 8        // coef j-splits (128 each)
#define COB 28      // ceil(7056/256)
#define COB2 30     // ceil(7680/256): padded coefT combine
#define EPT 8       // edges per thread
#define EST 200000  // EE/EPT
#define EBLK 782    // ceil(EST/256)
#define GON 40      // nodes per block in gather_out

#define F3NB 391    // flow blocks (256 nodes each, 1 node/lane)
#define KPAD 320    // padded K rows (37 chunks x 8 = 296 used, zero-filled past 293)

// coef, wave-uniform, read via scalar pipe (s_load from K$) in the flow kernel
__constant__ float ccoefT[KPAD * 24];

// ---------------- device bodies ----------------

__device__ __forceinline__ void mlp_part_body(int bid, const float* __restrict__ hin,
                                              const float* __restrict__ W,
                                              float* __restrict__ part, int jdim) {
    int it = bid & 15;
    int bs = bid >> 4;
    int tx = threadIdx.x;
    int il = tx & 63;
    int jg = tx >> 6;
    int i = it * 64 + il;
    int j0 = bs * 64;

    __shared__ float hs[8 * 64];
    for (int u = tx; u < 512; u += 256) {
        int b = u >> 6, lj = u & 63;
        hs[u] = hin[b * jdim + j0 + lj];
    }
    __syncthreads();

    float acc[8];
#pragma unroll
    for (int b = 0; b < 8; ++b) acc[b] = 0.0f;
#pragma unroll
    for (int jj = 0; jj < 16; ++jj) {
        int lj = jg * 16 + jj;
        float w = W[(size_t)(j0 + lj) * HH + i];
#pragma unroll
        for (int b = 0; b < 8; ++b) acc[b] += hs[b * 64 + lj] * w;
    }

    __shared__ float red[4][8][64];
#pragma unroll
    for (int b = 0; b < 8; ++b) red[jg][b][il] = acc[b];
    __syncthreads();
    for (int u = tx; u < 512; u += 256) {
        int b = u >> 6, ii = u & 63;
        float s = red[0][b][ii] + red[1][b][ii] + red[2][b][ii] + red[3][b][ii];
        part[(size_t)bs * 8192 + b * HH + it * 64 + ii] = s;
    }
}

__device__ __forceinline__ void mlp_comb_body(int bid, const float* __restrict__ part,
                                              int nsplit, const float* __restrict__ resid,
                                              const float* __restrict__ bias,
                                              float* __restrict__ hout) {
    int idx = bid * 256 + threadIdx.x;
    if (idx >= BB * HH) return;
    int i = idx & (HH - 1);
    float s = bias[i];
    if (resid) s += resid[idx];
    for (int bs = 0; bs < nsplit; ++bs) s += part[(size_t)bs * 8192 + idx];
    hout[idx] = fmaxf(s, 0.0f);
}

// count + capture rank (one atomic per edge; memory-side throughput-bound —
// rounds 5/6 showed ~60-70us irreducible, so hide it under the flow kernel)
__device__ __forceinline__ void count_body(int bid, const int* __restrict__ ei,
                                           int* __restrict__ cnt, int* __restrict__ rank) {
    int gid = bid * 256 + threadIdx.x;
    if (gid >= EST) return;
    int d[EPT];
#pragma unroll
    for (int j = 0; j < EPT; ++j) d[j] = ei[EE + gid + j * EST];
#pragma unroll
    for (int j = 0; j < EPT; ++j) {
        int p = atomicAdd(&cnt[d[j]], 1);
        rank[gid + j * EST] = p;
    }
}

__device__ __forceinline__ void bsum_body(int bid, const int* __restrict__ cnt,
                                          int* __restrict__ bsum) {
    __shared__ int red[256];
    int i = bid * 256 + threadIdx.x;
    red[threadIdx.x] = (i < NN) ? cnt[i] : 0;
    __syncthreads();
    for (int off = 128; off > 0; off >>= 1) {
        if ((int)threadIdx.x < off) red[threadIdx.x] += red[threadIdx.x + off];
        __syncthreads();
    }
    if (threadIdx.x == 0) bsum[bid] = red[0];
}

__device__ __forceinline__ void bscan_body(const int* __restrict__ bsum,
                                           int* __restrict__ bpre,
                                           int* __restrict__ offs) {
    __shared__ int A[512], Bf[512];
    int t = threadIdx.x;
    A[t] = (t < NB) ? bsum[t] : 0;
    A[t + 256] = (t + 256 < NB) ? bsum[t + 256] : 0;
    __syncthreads();
    int* s = A;
    int* d = Bf;
    for (int off = 1; off < 512; off <<= 1) {
        d[t] = s[t] + ((t >= off) ? s[t - off] : 0);
        int u = t + 256;
        d[u] = s[u] + ((u >= off) ? s[u - off] : 0);
        __syncthreads();
        int* tmp = s; s = d; d = tmp;
    }
    if (t < NB) bpre[t] = (t == 0) ? 0 : s[t - 1];
    int u = t + 256;
    if (u < NB) bpre[u] = s[u - 1];
    if (t == 0) offs[NN] = s[NB - 1];
}

__device__ __forceinline__ void offs_body(int bid, const int* __restrict__ cnt,
                                          const int* __restrict__ bpre,
                                          int* __restrict__ offs) {
    __shared__ int part[256];
    int t = threadIdx.x;
    int i = bid * 256 + t;
    int v = (i < NN) ? cnt[i] : 0;
    part[t] = v;
    __syncthreads();
    for (int off = 1; off < 256; off <<= 1) {
        int u = (t >= off) ? part[t - off] : 0;
        __syncthreads();
        part[t] += u;
        __syncthreads();
    }
    if (i < NN) offs[i] = bpre[bid] + part[t] - v;
}

// atomic-free fill: p = offs[dst] + rank[e]
__device__ __forceinline__ void fill_body(int bid, const int* __restrict__ ei,
                                          const float* __restrict__ ew,
                                          const int* __restrict__ offs,
                                          const int* __restrict__ rank,
                                          int2* __restrict__ csr) {
    int gid = bid * 256 + threadIdx.x;
    if (gid >= EST) return;
    int s[EPT], d[EPT], r[EPT];
    float w[EPT];
#pragma unroll
    for (int j = 0; j < EPT; ++j) {
        int e = gid + j * EST;
        s[j] = ei[e];
        d[j] = ei[EE + e];
        w[j] = ew[e];
        r[j] = rank[e];
    }
#pragma unroll
    for (int j = 0; j < EPT; ++j) {
        int p = offs[d[j]] + r[j];
        int2 v;
        v.x = s[j];
        v.y = __float_as_int(w[j]);
        csr[p] = v;
    }
}

// flow3: explicit async pipeline. 4 independent waves/block, 1 node/lane.
// Each wave streams all 296 (padded) z-rows for its 64 nodes through a 4-buffer
// LDS ring filled by global_load_lds (256B per op), 3 chunks (24 ops) kept in
// flight via counted "s_waitcnt vmcnt(24)". coef rows come from __constant__
// via the scalar pipe. No cross-wave reduce, no barriers.
__device__ __forceinline__ void flow3_body(int bid, const float* __restrict__ Z,
                                           float* __restrict__ fout) {
    __shared__ float zl[4][4][8][64];   // [wave][buf][row][lane] = 32 KB

    int t = threadIdx.x;
    int lane = t & 63;
    int wu = __builtin_amdgcn_readfirstlane(t >> 6);   // wave id (uniform)

    int n = bid * 256 + (wu << 6) + lane;
    int nn = (n < NN) ? n : (NN - 1);
    const float* zn = Z + nn;

    float acc[24];
#pragma unroll
    for (int j = 0; j < 24; ++j) acc[j] = 0.0f;

    auto issue = [&](int cp) {
        int b = cp & 3;
#pragma unroll
        for (int d = 0; d < 8; ++d) {
            int r = cp * 8 + d;
            int rz = (r < KK) ? r : (KK - 1);   // rows >= KK multiply zero coef
            __builtin_amdgcn_global_load_lds(
                (__attribute__((address_space(1))) unsigned int*)(zn + (size_t)rz * NN),
                (__attribute__((address_space(3))) unsigned int*)(&zl[wu][b][d][0]),
                4, 0, 0);
        }
    };

    issue(0); issue(1); issue(2);

#pragma unroll 1
    for (int c = 0; c < 37; ++c) {
        issue(c + 3);                            // ring-safe: buf (c+3)&3 consumed at c-1
        asm volatile("s_waitcnt vmcnt(24)" ::: "memory");   // chunk c landed
        __builtin_amdgcn_sched_barrier(0);
        int b = c & 3;
#pragma unroll
        for (int d = 0; d < 8; ++d) {
            float z = zl[wu][b][d][lane];
            const float* cf = &ccoefT[(c * 8 + d) * 24];   // uniform -> s_load
#pragma unroll
            for (int j = 0; j < 24; ++j) acc[j] = fmaf(cf[j], z, acc[j]);
        }
    }

    if (n < NN) {
        float buf4[24];
#pragma unroll
        for (int j = 0; j < 24; ++j) buf4[j] = XS_HALF * acc[j];
        float4* fr = (float4*)(fout + (size_t)n * 24);
#pragma unroll
        for (int q = 0; q < 6; ++q) fr[q] = ((const float4*)buf4)[q];
    }
}

__device__ __forceinline__ void reg_body(const float* __restrict__ coef,
                                         float* __restrict__ out_reg) {
    __shared__ float red[256];
    float s = 0.0f;
    for (int i = threadIdx.x; i < 3 * BB * KK; i += 256) {
        float v = coef[i];
        s += v * v;
    }
    red[threadIdx.x] = s;
    __syncthreads();
    for (int off = 128; off > 0; off >>= 1) {
        if ((int)threadIdx.x < off) red[threadIdx.x] += red[threadIdx.x + off];
        __syncthreads();
    }
    if (threadIdx.x == 0) out_reg[0] = 1e-4f * sqrtf(red[0]);
}

// ---------------- kernels ----------------

__global__ void K_part(const float* __restrict__ hin, const float* __restrict__ W,
                       float* __restrict__ part, int jdim) {
    mlp_part_body(blockIdx.x, hin, W, part, jdim);
}

__global__ void K_comb(const float* __restrict__ part, int nsplit,
                       const float* __restrict__ resid, const float* __restrict__ bias,
                       float* __restrict__ hout) {
    mlp_comb_body(blockIdx.x, part, nsplit, resid, bias, hout);
}

__global__ void k_coef_part(const float* __restrict__ h,
                            const float* __restrict__ Wx,
                            const float* __restrict__ Wy,
                            const float* __restrict__ Wz,
                            float* __restrict__ cpart) {
    int s = blockIdx.x / COB;
    int blk = blockIdx.x % COB;
    int o = blk * 256 + threadIdx.x;
    if (o >= 3 * BB * KK) return;
    int t = o / (BB * KK);
    int r = o % (BB * KK);
    int b = r / KK, k = r % KK;
    const float* W = (t == 0) ? Wx : ((t == 1) ? Wy : Wz);
    const float* hr = h + b * HH;
    int j0 = s * 128;
    float acc = 0.0f;
#pragma unroll 8
    for (int j = 0; j < 128; ++j) acc += hr[j0 + j] * W[(size_t)(j0 + j) * KK + k];
    cpart[(size_t)s * 7056 + o] = acc;
}

// combine partials and write TRANSPOSED padded coefT[k][b*3+t]; rows k>=294 zeroed
__global__ void k_coef_comb(const float* __restrict__ cpart,
                            const float* __restrict__ bx,
                            const float* __restrict__ by,
                            const float* __restrict__ bz,
                            float* __restrict__ coefT) {
    int o = blockIdx.x * 256 + threadIdx.x;
    if (o >= KPAD * 24) return;
    if (o >= 3 * BB * KK) {      // pad region: linear indices [7056, 7680) == rows k>=294
        coefT[o] = 0.0f;
        return;
    }
    int t = o / (BB * KK);
    int r = o % (BB * KK);
    int b = r / KK;
    int k = r % KK;
    float s = ((t == 0) ? bx : ((t == 1) ? by : bz))[k];
#pragma unroll
    for (int i = 0; i < CS; ++i) s += cpart[(size_t)i * 7056 + o];
    coefT[k * 24 + b * 3 + t] = s;
}

// THE overlap kernel: flow (VALU+VMEM pipeline) co-resident with count (memory-
// side atomics) + reg. All 1174 blocks fit on-device at once (37.6MB LDS < 40.9).
__global__ void K_flow_count_reg(const float* __restrict__ Z, float* __restrict__ fout,
                                 const int* __restrict__ ei, int* __restrict__ cnt,
                                 int* __restrict__ rank, const float* __restrict__ coefT,
                                 float* __restrict__ out_reg) {
    if (blockIdx.x < F3NB) flow3_body(blockIdx.x, Z, fout);
    else if (blockIdx.x < F3NB + EBLK) count_body(blockIdx.x - F3NB, ei, cnt, rank);
    else reg_body(coefT, out_reg);
}

__global__ void K_bsum(const int* __restrict__ cnt, int* __restrict__ bsum) {
    bsum_body(blockIdx.x, cnt, bsum);
}

__global__ void K_bscan(const int* __restrict__ bsum, int* __restrict__ bpre,
                        int* __restrict__ offs) {
    bscan_body(bsum, bpre, offs);
}

__global__ void K_offs(const int* __restrict__ cnt, const int* __restrict__ bpre,
                       int* __restrict__ offs) {
    offs_body(blockIdx.x, cnt, bpre, offs);
}

__global__ void K_fill(const int* __restrict__ ei, const float* __restrict__ ew,
                       const int* __restrict__ offs, const int* __restrict__ rank,
                       int2* __restrict__ csr) {
    fill_body(blockIdx.x, ei, ew, offs, rank, csr);
}

// ---------------- diffusion ----------------
// unroll-4 batched gather: 4 csr entries then 4 independent f-row gathers in
// flight per thread (latency-bound fix); weight-sum computed inline (deg fold).
__global__ void k_gather(const int* __restrict__ offs, const int2* __restrict__ csr,
                         const float* __restrict__ fin, float* __restrict__ fout) {
    int idx = blockIdx.x * 256 + threadIdx.x;   // NN*6
    if (idx >= NN * 6) return;
    int n = idx / 6;
    int q = idx - n * 6;
    int beg = offs[n], end = offs[n + 1];
    const float4* f4 = (const float4*)fin;
    float4 acc = make_float4(0.f, 0.f, 0.f, 0.f);
    float wsum = 0.0f;
    int i = beg;
    for (; i + 4 <= end; i += 4) {
        int2 e[4];
#pragma unroll
        for (int u = 0; u < 4; ++u) e[u] = csr[i + u];
        float4 v[4];
#pragma unroll
        for (int u = 0; u < 4; ++u) v[u] = f4[(size_t)e[u].x * 6 + q];
#pragma unroll
        for (int u = 0; u < 4; ++u) {
            float w = __int_as_float(e[u].y);
            wsum += w;
            acc.x += w * v[u].x;
            acc.y += w * v[u].y;
            acc.z += w * v[u].z;
            acc.w += w * v[u].w;
        }
    }
    for (; i < end; ++i) {
        int2 e = csr[i];
        float w = __int_as_float(e.y);
        float4 fv = f4[(size_t)e.x * 6 + q];
        wsum += w;
        acc.x += w * fv.x;
        acc.y += w * fv.y;
        acc.z += w * fv.z;
        acc.w += w * fv.w;
    }
    float inv = 0.5f / fmaxf(wsum, 1e-6f);
    float4 fo = f4[(size_t)n * 6 + q];
    float4 r;
    r.x = 0.5f * fo.x + inv * acc.x;
    r.y = 0.5f * fo.y + inv * acc.y;
    r.z = 0.5f * fo.z + inv * acc.z;
    r.w = 0.5f * fo.w + inv * acc.w;
    ((float4*)fout)[(size_t)n * 6 + q] = r;
}

// last diffusion step: gather + combine + transposed write to out[b][n][c]
__global__ void k_gather_out(const int* __restrict__ offs, const int2* __restrict__ csr,
                             const float* __restrict__ fin, float* __restrict__ out) {
    __shared__ float ls[GON * 24];
    int t = threadIdx.x;
    int n0 = blockIdx.x * GON;
    if (t < GON * 6) {
        int ln = t / 6, q = t - 6 * ln;
        int n = n0 + ln;
        if (n < NN) {
            int beg = offs[n], end = offs[n + 1];
            const float4* f4 = (const float4*)fin;
            float4 acc = make_float4(0.f, 0.f, 0.f, 0.f);
            float wsum = 0.0f;
            int i = beg;
            for (; i + 4 <= end; i += 4) {
                int2 e[4];
#pragma unroll
                for (int u = 0; u < 4; ++u) e[u] = csr[i + u];
                float4 v[4];
#pragma unroll
                for (int u = 0; u < 4; ++u) v[u] = f4[(size_t)e[u].x * 6 + q];
#pragma unroll
                for (int u = 0; u < 4; ++u) {
                    float w = __int_as_float(e[u].y);
                    wsum += w;
                    acc.x += w * v[u].x;
                    acc.y += w * v[u].y;
                    acc.z += w * v[u].z;
                    acc.w += w * v[u].w;
                }
            }
            for (; i < end; ++i) {
                int2 e = csr[i];
                float w = __int_as_float(e.y);
                float4 fv = f4[(size_t)e.x * 6 + q];
                wsum += w;
                acc.x += w * fv.x;
                acc.y += w * fv.y;
                acc.z += w * fv.z;
                acc.w += w * fv.w;
            }
            float inv = 0.5f / fmaxf(wsum, 1e-6f);
            float4 fo = f4[(size_t)n * 6 + q];
            float* d = &ls[ln * 24 + q * 4];
            d[0] = 0.5f * fo.x + inv * acc.x;
            d[1] = 0.5f * fo.y + inv * acc.y;
            d[2] = 0.5f * fo.z + inv * acc.z;
            d[3] = 0.5f * fo.w + inv * acc.w;
        }
    }
    __syncthreads();
    int cnt = NN - n0; if (cnt > GON) cnt = GON;
    int per_b = cnt * 3;
    for (int b = 0; b < BB; ++b) {
        for (int u = t; u < per_b; u += 256) {
            int n = u / 3;
            int c = u - 3 * n;
            out[(size_t)b * (NN * 3) + (size_t)n0 * 3 + u] = ls[n * 24 + b * 3 + c];
        }
    }
}

extern "C" void kernel_launch(void* const* d_in, const int* in_sizes, int n_in,
                              void* d_out, int out_size, void* d_ws, size_t ws_size,
                              hipStream_t stream) {
    const float* latent = (const float*)d_in[0];
    const float* W0 = (const float*)d_in[1];
    const float* b0 = (const float*)d_in[2];
    const float* W1 = (const float*)d_in[3];
    const float* b1 = (const float*)d_in[4];
    const float* W2 = (const float*)d_in[5];
    const float* b2 = (const float*)d_in[6];
    const float* W3 = (const float*)d_in[7];
    const float* b3 = (const float*)d_in[8];
    const float* Wx = (const float*)d_in[9];
    const float* bx = (const float*)d_in[10];
    const float* Wy = (const float*)d_in[11];
    const float* by = (const float*)d_in[12];
    const float* Wz = (const float*)d_in[13];
    const float* bz = (const float*)d_in[14];
    const float* Z  = (const float*)d_in[15];
    const float* ew = (const float*)d_in[16];
    const int*   ei = (const int*)d_in[17];
    float* out = (float*)d_out;

    float* p = (float*)d_ws;
    float* h_a     = p; p += 8192;
    float* h_b     = p; p += 8192;
    float* hp      = p; p += 16 * 8192;
    float* coef    = p; p += KPAD * 24;       // padded coefT
    float* cpart   = p; p += CS * 7056;
    int*   cnt     = (int*)p; p += 100000;
    int*   offs    = (int*)p; p += 100016;
    int*   bsum    = (int*)p; p += 512;
    int*   bpre    = (int*)p; p += 512;
    int*   rank    = (int*)p; p += 1600000;
    int2*  csr     = (int2*)p; p += 2 * 1600000;
    float* fpart   = p; p += (size_t)2 * NN * 24;   // f0, f1 ping-pong

    hipMemsetAsync(cnt, 0, NN * sizeof(int), stream);

    // -------- phase 1: MLP chain + coef (serial, small) --------
    K_part<<<32, 256, 0, stream>>>(latent, W0, hp, LAT);
    K_comb<<<32, 256, 0, stream>>>(hp, 2, nullptr, b0, h_a);
    K_part<<<256, 256, 0, stream>>>(h_a, W1, hp, HH);
    K_comb<<<32, 256, 0, stream>>>(hp, 16, h_a, b1, h_b);
    K_part<<<256, 256, 0, stream>>>(h_b, W2, hp, HH);
    K_comb<<<32, 256, 0, stream>>>(hp, 16, h_b, b2, h_a);
    K_part<<<256, 256, 0, stream>>>(h_a, W3, hp, HH);
    K_comb<<<32, 256, 0, stream>>>(hp, 16, h_a, b3, h_b);
    k_coef_part<<<COB * CS, 256, 0, stream>>>(h_b, Wx, Wy, Wz, cpart);
    k_coef_comb<<<COB2, 256, 0, stream>>>(cpart, bx, by, bz, coef);
    hipMemcpyToSymbolAsync(HIP_SYMBOL(ccoefT), coef, KPAD * 24 * sizeof(float), 0,
                           hipMemcpyDeviceToDevice, stream);

    // -------- phase 2: flow OVERLAPPED with edge count (independent work) --------
    float* f0 = fpart;
    float* f1 = fpart + (size_t)NN * 24;
    K_flow_count_reg<<<F3NB + EBLK + 1, 256, 0, stream>>>(Z, f0, ei, cnt, rank, coef,
                                                          out + (size_t)BB * NN * 3);

    // -------- phase 3: scan + fill + diffusion --------
    K_bsum<<<NB, 256, 0, stream>>>(cnt, bsum);
    K_bscan<<<1, 256, 0, stream>>>(bsum, bpre, offs);
    K_offs<<<NB, 256, 0, stream>>>(cnt, bpre, offs);
    K_fill<<<EBLK, 256, 0, stream>>>(ei, ew, offs, rank, csr);

    k_gather<<<(NN * 6 + 255) / 256, 256, 0, stream>>>(offs, csr, f0, f1);
    k_gather<<<(NN * 6 + 255) / 256, 256, 0, stream>>>(offs, csr, f1, f0);
    k_gather_out<<<(NN + GON - 1) / GON, 256, 0, stream>>>(offs, csr, f0, out);
}

// Round 10
// 486.800 us; speedup vs baseline: 1.0463x; 1.0463x over previous
//
#include <hip/hip_runtime.h>
#include <math.h>

#define BB 8
#define LAT 128
#define HH 1024
#define KK 294
#define NN 100000
#define EE 1600000
#define NSTEPS 3
#define XS_HALF 64.0f

#define NB 391      // ceil(NN/256)
#define CS 8        // coef j-splits (128 each)
#define COB 28      // ceil(7056/256)
#define COB2 30     // ceil(7680/256): padded coefT combine
#define EPT 8       // edges per thread
#define EST 200000  // EE/EPT
#define EBLK 782    // ceil(EST/256)
#define QA 196      // count blocks per quarter (quarters: 196,196,196,194)
#define GON 40      // nodes per block in gather_out

#define F3NB 391    // flow blocks (256 nodes each, 1 node/lane)
#define KPAD 320    // padded K rows (37 chunks x 8 = 296 used, zero-filled past 293)

// coef, wave-uniform, read via scalar pipe (s_load from K$) in the flow kernel
__constant__ float ccoefT[KPAD * 24];

// ---------------- device bodies ----------------

__device__ __forceinline__ void mlp_part_body(int bid, const float* __restrict__ hin,
                                              const float* __restrict__ W,
                                              float* __restrict__ part, int jdim) {
    int it = bid & 15;
    int bs = bid >> 4;
    int tx = threadIdx.x;
    int il = tx & 63;
    int jg = tx >> 6;
    int i = it * 64 + il;
    int j0 = bs * 64;

    __shared__ float hs[8 * 64];
    for (int u = tx; u < 512; u += 256) {
        int b = u >> 6, lj = u & 63;
        hs[u] = hin[b * jdim + j0 + lj];
    }
    __syncthreads();

    float acc[8];
#pragma unroll
    for (int b = 0; b < 8; ++b) acc[b] = 0.0f;
#pragma unroll
    for (int jj = 0; jj < 16; ++jj) {
        int lj = jg * 16 + jj;
        float w = W[(size_t)(j0 + lj) * HH + i];
#pragma unroll
        for (int b = 0; b < 8; ++b) acc[b] += hs[b * 64 + lj] * w;
    }

    __shared__ float red[4][8][64];
#pragma unroll
    for (int b = 0; b < 8; ++b) red[jg][b][il] = acc[b];
    __syncthreads();
    for (int u = tx; u < 512; u += 256) {
        int b = u >> 6, ii = u & 63;
        float s = red[0][b][ii] + red[1][b][ii] + red[2][b][ii] + red[3][b][ii];
        part[(size_t)bs * 8192 + b * HH + it * 64 + ii] = s;
    }
}

__device__ __forceinline__ void mlp_comb_body(int bid, const float* __restrict__ part,
                                              int nsplit, const float* __restrict__ resid,
                                              const float* __restrict__ bias,
                                              float* __restrict__ hout) {
    int idx = bid * 256 + threadIdx.x;
    if (idx >= BB * HH) return;
    int i = idx & (HH - 1);
    float s = bias[i];
    if (resid) s += resid[idx];
    for (int bs = 0; bs < nsplit; ++bs) s += part[(size_t)bs * 8192 + idx];
    hout[idx] = fmaxf(s, 0.0f);
}

// count + capture rank. gbid is the GLOBAL count block id [0, EBLK): quarters of
// the edge list are hidden under successive MLP-chain dispatches (atomics overlap
// with compute-bound partners; r9 showed they serialize against memory-bound ones).
__device__ __forceinline__ void count_body(int gbid, const int* __restrict__ ei,
                                           int* __restrict__ cnt, int* __restrict__ rank) {
    int gid = gbid * 256 + threadIdx.x;
    if (gid >= EST) return;
    int d[EPT];
#pragma unroll
    for (int j = 0; j < EPT; ++j) d[j] = ei[EE + gid + j * EST];
#pragma unroll
    for (int j = 0; j < EPT; ++j) {
        int p = atomicAdd(&cnt[d[j]], 1);
        rank[gid + j * EST] = p;
    }
}

__device__ __forceinline__ void bsum_body(int bid, const int* __restrict__ cnt,
                                          int* __restrict__ bsum) {
    __shared__ int red[256];
    int i = bid * 256 + threadIdx.x;
    red[threadIdx.x] = (i < NN) ? cnt[i] : 0;
    __syncthreads();
    for (int off = 128; off > 0; off >>= 1) {
        if ((int)threadIdx.x < off) red[threadIdx.x] += red[threadIdx.x + off];
        __syncthreads();
    }
    if (threadIdx.x == 0) bsum[bid] = red[0];
}

__device__ __forceinline__ void bscan_body(const int* __restrict__ bsum,
                                           int* __restrict__ bpre,
                                           int* __restrict__ offs) {
    __shared__ int A[512], Bf[512];
    int t = threadIdx.x;
    A[t] = (t < NB) ? bsum[t] : 0;
    A[t + 256] = (t + 256 < NB) ? bsum[t + 256] : 0;
    __syncthreads();
    int* s = A;
    int* d = Bf;
    for (int off = 1; off < 512; off <<= 1) {
        d[t] = s[t] + ((t >= off) ? s[t - off] : 0);
        int u = t + 256;
        d[u] = s[u] + ((u >= off) ? s[u - off] : 0);
        __syncthreads();
        int* tmp = s; s = d; d = tmp;
    }
    if (t < NB) bpre[t] = (t == 0) ? 0 : s[t - 1];
    int u = t + 256;
    if (u < NB) bpre[u] = s[u - 1];
    if (t == 0) offs[NN] = s[NB - 1];
}

__device__ __forceinline__ void offs_body(int bid, const int* __restrict__ cnt,
                                          const int* __restrict__ bpre,
                                          int* __restrict__ offs) {
    __shared__ int part[256];
    int t = threadIdx.x;
    int i = bid * 256 + t;
    int v = (i < NN) ? cnt[i] : 0;
    part[t] = v;
    __syncthreads();
    for (int off = 1; off < 256; off <<= 1) {
        int u = (t >= off) ? part[t - off] : 0;
        __syncthreads();
        part[t] += u;
        __syncthreads();
    }
    if (i < NN) offs[i] = bpre[bid] + part[t] - v;
}

// atomic-free fill: p = offs[dst] + rank[e]
__device__ __forceinline__ void fill_body(int bid, const int* __restrict__ ei,
                                          const float* __restrict__ ew,
                                          const int* __restrict__ offs,
                                          const int* __restrict__ rank,
                                          int2* __restrict__ csr) {
    int gid = bid * 256 + threadIdx.x;
    if (gid >= EST) return;
    int s[EPT], d[EPT], r[EPT];
    float w[EPT];
#pragma unroll
    for (int j = 0; j < EPT; ++j) {
        int e = gid + j * EST;
        s[j] = ei[e];
        d[j] = ei[EE + e];
        w[j] = ew[e];
        r[j] = rank[e];
    }
#pragma unroll
    for (int j = 0; j < EPT; ++j) {
        int p = offs[d[j]] + r[j];
        int2 v;
        v.x = s[j];
        v.y = __float_as_int(w[j]);
        csr[p] = v;
    }
}

// flow3: explicit async pipeline. 4 independent waves/block, 1 node/lane.
// Each wave streams all 296 (padded) z-rows for its 64 nodes through a 4-buffer
// LDS ring filled by global_load_lds (256B per op), 3 chunks (24 ops) kept in
// flight via counted "s_waitcnt vmcnt(24)". coef rows come from __constant__
// via the scalar pipe. No cross-wave reduce, no barriers.
__device__ __forceinline__ void flow3_body(int bid, const float* __restrict__ Z,
                                           float* __restrict__ fout) {
    __shared__ float zl[4][4][8][64];   // [wave][buf][row][lane] = 32 KB

    int t = threadIdx.x;
    int lane = t & 63;
    int wu = __builtin_amdgcn_readfirstlane(t >> 6);   // wave id (uniform)

    int n = bid * 256 + (wu << 6) + lane;
    int nn = (n < NN) ? n : (NN - 1);
    const float* zn = Z + nn;

    float acc[24];
#pragma unroll
    for (int j = 0; j < 24; ++j) acc[j] = 0.0f;

    auto issue = [&](int cp) {
        int b = cp & 3;
#pragma unroll
        for (int d = 0; d < 8; ++d) {
            int r = cp * 8 + d;
            int rz = (r < KK) ? r : (KK - 1);   // rows >= KK multiply zero coef
            __builtin_amdgcn_global_load_lds(
                (__attribute__((address_space(1))) unsigned int*)(zn + (size_t)rz * NN),
                (__attribute__((address_space(3))) unsigned int*)(&zl[wu][b][d][0]),
                4, 0, 0);
        }
    };

    issue(0); issue(1); issue(2);

#pragma unroll 1
    for (int c = 0; c < 37; ++c) {
        issue(c + 3);                            // ring-safe: buf (c+3)&3 consumed at c-1
        asm volatile("s_waitcnt vmcnt(24)" ::: "memory");   // chunk c landed
        __builtin_amdgcn_sched_barrier(0);
        int b = c & 3;
#pragma unroll
        for (int d = 0; d < 8; ++d) {
            float z = zl[wu][b][d][lane];
            const float* cf = &ccoefT[(c * 8 + d) * 24];   // uniform -> s_load
#pragma unroll
            for (int j = 0; j < 24; ++j) acc[j] = fmaf(cf[j], z, acc[j]);
        }
    }

    if (n < NN) {
        float buf4[24];
#pragma unroll
        for (int j = 0; j < 24; ++j) buf4[j] = XS_HALF * acc[j];
        float4* fr = (float4*)(fout + (size_t)n * 24);
#pragma unroll
        for (int q = 0; q < 6; ++q) fr[q] = ((const float4*)buf4)[q];
    }
}

__device__ __forceinline__ void reg_body(const float* __restrict__ coef,
                                         float* __restrict__ out_reg) {
    __shared__ float red[256];
    float s = 0.0f;
    for (int i = threadIdx.x; i < 3 * BB * KK; i += 256) {
        float v = coef[i];
        s += v * v;
    }
    red[threadIdx.x] = s;
    __syncthreads();
    for (int off = 128; off > 0; off >>= 1) {
        if ((int)threadIdx.x < off) red[threadIdx.x] += red[threadIdx.x + off];
        __syncthreads();
    }
    if (threadIdx.x == 0) out_reg[0] = 1e-4f * sqrtf(red[0]);
}

// ---------------- fused kernels: count quarters ride the MLP chain ----------------

__global__ void K1_mlp0_cnt(const float* __restrict__ latent, const float* __restrict__ W0,
                            float* __restrict__ part, const int* __restrict__ ei,
                            int* __restrict__ cnt, int* __restrict__ rank) {
    if (blockIdx.x < 32) mlp_part_body(blockIdx.x, latent, W0, part, LAT);
    else count_body(blockIdx.x - 32, ei, cnt, rank);                    // q0: 0..195
}

__global__ void K2_comb0_cnt(const float* __restrict__ part, const float* __restrict__ b0,
                             float* __restrict__ hout, const int* __restrict__ ei,
                             int* __restrict__ cnt, int* __restrict__ rank) {
    if (blockIdx.x < 32) mlp_comb_body(blockIdx.x, part, 2, nullptr, b0, hout);
    else count_body(blockIdx.x - 32 + QA, ei, cnt, rank);               // q1: 196..391
}

__global__ void K3_mlp1_cnt(const float* __restrict__ hin, const float* __restrict__ W1,
                            float* __restrict__ part, const int* __restrict__ ei,
                            int* __restrict__ cnt, int* __restrict__ rank) {
    if (blockIdx.x < 256) mlp_part_body(blockIdx.x, hin, W1, part, HH);
    else count_body(blockIdx.x - 256 + 2 * QA, ei, cnt, rank);          // q2: 392..587
}

__global__ void K4_comb1_cnt(const float* __restrict__ part, const float* __restrict__ resid,
                             const float* __restrict__ b1, float* __restrict__ hout,
                             const int* __restrict__ ei, int* __restrict__ cnt,
                             int* __restrict__ rank) {
    if (blockIdx.x < 32) mlp_comb_body(blockIdx.x, part, 16, resid, b1, hout);
    else count_body(blockIdx.x - 32 + 3 * QA, ei, cnt, rank);           // q3: 588..781
}

__global__ void K5_mlp2_bsum(const float* __restrict__ hin, const float* __restrict__ W2,
                             float* __restrict__ part, const int* __restrict__ cnt,
                             int* __restrict__ bsum) {
    if (blockIdx.x < 256) mlp_part_body(blockIdx.x, hin, W2, part, HH);
    else bsum_body(blockIdx.x - 256, cnt, bsum);
}

__global__ void K6_comb2_bscan(const float* __restrict__ part, const float* __restrict__ resid,
                               const float* __restrict__ b2, float* __restrict__ hout,
                               const int* __restrict__ bsum, int* __restrict__ bpre,
                               int* __restrict__ offs) {
    if (blockIdx.x < 32) mlp_comb_body(blockIdx.x, part, 16, resid, b2, hout);
    else bscan_body(bsum, bpre, offs);
}

__global__ void K7_mlp3_offs(const float* __restrict__ hin, const float* __restrict__ W3,
                             float* __restrict__ part, const int* __restrict__ cnt,
                             const int* __restrict__ bpre, int* __restrict__ offs) {
    if (blockIdx.x < 256) mlp_part_body(blockIdx.x, hin, W3, part, HH);
    else offs_body(blockIdx.x - 256, cnt, bpre, offs);
}

__global__ void K8_comb3(const float* __restrict__ part, const float* __restrict__ resid,
                         const float* __restrict__ b3, float* __restrict__ hout) {
    mlp_comb_body(blockIdx.x, part, 16, resid, b3, hout);
}

__global__ void k_coef_part(const float* __restrict__ h,
                            const float* __restrict__ Wx,
                            const float* __restrict__ Wy,
                            const float* __restrict__ Wz,
                            float* __restrict__ cpart) {
    int s = blockIdx.x / COB;
    int blk = blockIdx.x % COB;
    int o = blk * 256 + threadIdx.x;
    if (o >= 3 * BB * KK) return;
    int t = o / (BB * KK);
    int r = o % (BB * KK);
    int b = r / KK, k = r % KK;
    const float* W = (t == 0) ? Wx : ((t == 1) ? Wy : Wz);
    const float* hr = h + b * HH;
    int j0 = s * 128;
    float acc = 0.0f;
#pragma unroll 8
    for (int j = 0; j < 128; ++j) acc += hr[j0 + j] * W[(size_t)(j0 + j) * KK + k];
    cpart[(size_t)s * 7056 + o] = acc;
}

// combine partials and write TRANSPOSED padded coefT[k][b*3+t]; rows k>=294 zeroed
__global__ void k_coef_comb(const float* __restrict__ cpart,
                            const float* __restrict__ bx,
                            const float* __restrict__ by,
                            const float* __restrict__ bz,
                            float* __restrict__ coefT) {
    int o = blockIdx.x * 256 + threadIdx.x;
    if (o >= KPAD * 24) return;
    if (o >= 3 * BB * KK) {      // pad region: linear indices [7056, 7680) == rows k>=294
        coefT[o] = 0.0f;
        return;
    }
    int t = o / (BB * KK);
    int r = o % (BB * KK);
    int b = r / KK;
    int k = r % KK;
    float s = ((t == 0) ? bx : ((t == 1) ? by : bz))[k];
#pragma unroll
    for (int i = 0; i < CS; ++i) s += cpart[(size_t)i * 7056 + o];
    coefT[k * 24 + b * 3 + t] = s;
}

// flow (compute+stream pipeline) overlapped with fill (plain scattered stores —
// no coherence-point serialization, unlike r9's count atomics) + reg.
__global__ void K_flow_fill_reg(const float* __restrict__ Z, float* __restrict__ fout,
                                const int* __restrict__ ei, const float* __restrict__ ew,
                                const int* __restrict__ offs, const int* __restrict__ rank,
                                int2* __restrict__ csr, const float* __restrict__ coefT,
                                float* __restrict__ out_reg) {
    if (blockIdx.x < F3NB) flow3_body(blockIdx.x, Z, fout);
    else if (blockIdx.x < F3NB + EBLK) fill_body(blockIdx.x - F3NB, ei, ew, offs, rank, csr);
    else reg_body(coefT, out_reg);
}

// ---------------- diffusion ----------------
// unroll-4 batched gather: 4 csr entries then 4 independent f-row gathers in
// flight per thread (latency-bound fix); weight-sum computed inline (deg fold).
__global__ void k_gather(const int* __restrict__ offs, const int2* __restrict__ csr,
                         const float* __restrict__ fin, float* __restrict__ fout) {
    int idx = blockIdx.x * 256 + threadIdx.x;   // NN*6
    if (idx >= NN * 6) return;
    int n = idx / 6;
    int q = idx - n * 6;
    int beg = offs[n], end = offs[n + 1];
    const float4* f4 = (const float4*)fin;
    float4 acc = make_float4(0.f, 0.f, 0.f, 0.f);
    float wsum = 0.0f;
    int i = beg;
    for (; i + 4 <= end; i += 4) {
        int2 e[4];
#pragma unroll
        for (int u = 0; u < 4; ++u) e[u] = csr[i + u];
        float4 v[4];
#pragma unroll
        for (int u = 0; u < 4; ++u) v[u] = f4[(size_t)e[u].x * 6 + q];
#pragma unroll
        for (int u = 0; u < 4; ++u) {
            float w = __int_as_float(e[u].y);
            wsum += w;
            acc.x += w * v[u].x;
            acc.y += w * v[u].y;
            acc.z += w * v[u].z;
            acc.w += w * v[u].w;
        }
    }
    for (; i < end; ++i) {
        int2 e = csr[i];
        float w = __int_as_float(e.y);
        float4 fv = f4[(size_t)e.x * 6 + q];
        wsum += w;
        acc.x += w * fv.x;
        acc.y += w * fv.y;
        acc.z += w * fv.z;
        acc.w += w * fv.w;
    }
    float inv = 0.5f / fmaxf(wsum, 1e-6f);
    float4 fo = f4[(size_t)n * 6 + q];
    float4 r;
    r.x = 0.5f * fo.x + inv * acc.x;
    r.y = 0.5f * fo.y + inv * acc.y;
    r.z = 0.5f * fo.z + inv * acc.z;
    r.w = 0.5f * fo.w + inv * acc.w;
    ((float4*)fout)[(size_t)n * 6 + q] = r;
}

// last diffusion step: gather + combine + transposed write to out[b][n][c]
__global__ void k_gather_out(const int* __restrict__ offs, const int2* __restrict__ csr,
                             const float* __restrict__ fin, float* __restrict__ out) {
    __shared__ float ls[GON * 24];
    int t = threadIdx.x;
    int n0 = blockIdx.x * GON;
    if (t < GON * 6) {
        int ln = t / 6, q = t - 6 * ln;
        int n = n0 + ln;
        if (n < NN) {
            int beg = offs[n], end = offs[n + 1];
            const float4* f4 = (const float4*)fin;
            float4 acc = make_float4(0.f, 0.f, 0.f, 0.f);
            float wsum = 0.0f;
            int i = beg;
            for (; i + 4 <= end; i += 4) {
                int2 e[4];
#pragma unroll
                for (int u = 0; u < 4; ++u) e[u] = csr[i + u];
                float4 v[4];
#pragma unroll
                for (int u = 0; u < 4; ++u) v[u] = f4[(size_t)e[u].x * 6 + q];
#pragma unroll
                for (int u = 0; u < 4; ++u) {
                    float w = __int_as_float(e[u].y);
                    wsum += w;
                    acc.x += w * v[u].x;
                    acc.y += w * v[u].y;
                    acc.z += w * v[u].z;
                    acc.w += w * v[u].w;
                }
            }
            for (; i < end; ++i) {
                int2 e = csr[i];
                float w = __int_as_float(e.y);
                float4 fv = f4[(size_t)e.x * 6 + q];
                wsum += w;
                acc.x += w * fv.x;
                acc.y += w * fv.y;
                acc.z += w * fv.z;
                acc.w += w * fv.w;
            }
            float inv = 0.5f / fmaxf(wsum, 1e-6f);
            float4 fo = f4[(size_t)n * 6 + q];
            float* d = &ls[ln * 24 + q * 4];
            d[0] = 0.5f * fo.x + inv * acc.x;
            d[1] = 0.5f * fo.y + inv * acc.y;
            d[2] = 0.5f * fo.z + inv * acc.z;
            d[3] = 0.5f * fo.w + inv * acc.w;
        }
    }
    __syncthreads();
    int cnt = NN - n0; if (cnt > GON) cnt = GON;
    int per_b = cnt * 3;
    for (int b = 0; b < BB; ++b) {
        for (int u = t; u < per_b; u += 256) {
            int n = u / 3;
            int c = u - 3 * n;
            out[(size_t)b * (NN * 3) + (size_t)n0 * 3 + u] = ls[n * 24 + b * 3 + c];
        }
    }
}

extern "C" void kernel_launch(void* const* d_in, const int* in_sizes, int n_in,
                              void* d_out, int out_size, void* d_ws, size_t ws_size,
                              hipStream_t stream) {
    const float* latent = (const float*)d_in[0];
    const float* W0 = (const float*)d_in[1];
    const float* b0 = (const float*)d_in[2];
    const float* W1 = (const float*)d_in[3];
    const float* b1 = (const float*)d_in[4];
    const float* W2 = (const float*)d_in[5];
    const float* b2 = (const float*)d_in[6];
    const float* W3 = (const float*)d_in[7];
    const float* b3 = (const float*)d_in[8];
    const float* Wx = (const float*)d_in[9];
    const float* bx = (const float*)d_in[10];
    const float* Wy = (const float*)d_in[11];
    const float* by = (const float*)d_in[12];
    const float* Wz = (const float*)d_in[13];
    const float* bz = (const float*)d_in[14];
    const float* Z  = (const float*)d_in[15];
    const float* ew = (const float*)d_in[16];
    const int*   ei = (const int*)d_in[17];
    float* out = (float*)d_out;

    float* p = (float*)d_ws;
    float* h_a     = p; p += 8192;
    float* h_b     = p; p += 8192;
    float* hp      = p; p += 16 * 8192;
    float* coef    = p; p += KPAD * 24;       // padded coefT
    float* cpart   = p; p += CS * 7056;
    int*   cnt     = (int*)p; p += 100000;
    int*   offs    = (int*)p; p += 100016;
    int*   bsum    = (int*)p; p += 512;
    int*   bpre    = (int*)p; p += 512;
    int*   rank    = (int*)p; p += 1600000;
    int2*  csr     = (int2*)p; p += 2 * 1600000;
    float* fpart   = p; p += (size_t)2 * NN * 24;   // f0, f1 ping-pong

    hipMemsetAsync(cnt, 0, NN * sizeof(int), stream);

    // -------- MLP chain with count quarters + scan riding along --------
    K1_mlp0_cnt<<<32 + QA, 256, 0, stream>>>(latent, W0, hp, ei, cnt, rank);
    K2_comb0_cnt<<<32 + QA, 256, 0, stream>>>(hp, b0, h_a, ei, cnt, rank);
    K3_mlp1_cnt<<<256 + QA, 256, 0, stream>>>(h_a, W1, hp, ei, cnt, rank);
    K4_comb1_cnt<<<32 + (EBLK - 3 * QA), 256, 0, stream>>>(hp, h_a, b1, h_b, ei, cnt, rank);
    K5_mlp2_bsum<<<256 + NB, 256, 0, stream>>>(h_b, W2, hp, cnt, bsum);
    K6_comb2_bscan<<<32 + 1, 256, 0, stream>>>(hp, h_b, b2, h_a, bsum, bpre, offs);
    K7_mlp3_offs<<<256 + NB, 256, 0, stream>>>(h_a, W3, hp, cnt, bpre, offs);
    K8_comb3<<<32, 256, 0, stream>>>(hp, h_a, b3, h_b);
    // coef projection (writes padded transposed coefT[k][24])
    k_coef_part<<<COB * CS, 256, 0, stream>>>(h_b, Wx, Wy, Wz, cpart);
    k_coef_comb<<<COB2, 256, 0, stream>>>(cpart, bx, by, bz, coef);
    hipMemcpyToSymbolAsync(HIP_SYMBOL(ccoefT), coef, KPAD * 24 * sizeof(float), 0,
                           hipMemcpyDeviceToDevice, stream);

    // -------- flow overlapped with fill (scatter stores, no atomics) --------
    float* f0 = fpart;
    float* f1 = fpart + (size_t)NN * 24;
    K_flow_fill_reg<<<F3NB + EBLK + 1, 256, 0, stream>>>(Z, f0, ei, ew, offs, rank, csr,
                                                         coef, out + (size_t)BB * NN * 3);

    // -------- diffusion --------
    k_gather<<<(NN * 6 + 255) / 256, 256, 0, stream>>>(offs, csr, f0, f1);
    k_gather<<<(NN * 6 + 255) / 256, 256, 0, stream>>>(offs, csr, f1, f0);
    k_gather_out<<<(NN + GON - 1) / GON, 256, 0, stream>>>(offs, csr, f0, out);
}